// Round 16
// baseline (76.510 us; speedup 1.0000x reference)
//
#include <hip/hip_runtime.h>

// CRF-RNN (C=2) on 56x56, 10 iterations in ONE kernel, plain launch.
// 196 blocks x 512 thr (8 waves) -> exactly 1 block/CU, 2 waves/SIMD.
//
// Math: s = sigmoid(q1-q0); d = (2u-1) - alpha - beta*t_sp/n_sp - gamma*t_bl/n_bl.
//  * spatial separable: row conv TRUNCATED to +-16 taps (exp(-17^2/18)=1e-7),
//    wave-uniform column mapping (wave w owns cols 2w,2w+1; lanes = y) ->
//    uniform ~9-quad loop, broadcast weight reads. Column fold; n_sp = Sx*Sy.
//  * bilateral: theta_beta=3 -> weight < 5e-17 outside +-16 intensity
//    buckets. Counting sort ONCE; per-pair weights are ITERATION-INVARIANT ->
//    precomputed at iter 0 into wband[16][768] (LDS, 49KB; 1 block/CU so
//    budget is 160KB). Iter 1..9 band loop = load w, load s_sh[m], FMA.
//    Band overflow (>768, impossible for this data) falls back to the exact
//    formula -> correct for any input.
//  * norms s-independent: iter-0 computes them, reciprocals in registers.
//
// Sync (r15, proven): zero-sentinel flow control, per-thread tight spin.
// Publish = leader lanes store s right out of the reduce (relaxed agent scope
// -> LLC, no cache maintenance), no pre-barrier (safe: detection of all-3136
// transitively implies every lane finished reading old state). Poll = each
// thread re-issues its 1-2 quad loads (sc0 sc1) immediately. One barrier.

namespace {

constexpr int NPIX = 3136;
constexpr int WIMG = 56;
constexpr int JPB  = 16;              // j-pixels per block
constexpr int NBLK = NPIX / JPB;      // 196 blocks = 1 per CU
constexpr int NTHR = 512;             // 8 waves
constexpr int NQ   = NPIX / 4;        // 784 quads
constexpr int NBUF = 9;               // publish buffers (syncs after iters 0..8)
constexpr int BAND = 16;              // intensity band (buckets)
constexpr int Q2   = NQ - NTHR;       // 272 threads own a second quad
constexpr int MAXB = 768;             // cached band pairs per j

constexpr float LOG2E = 1.4426950408889634f;
constexpr float C1 = -LOG2E / 18.0f;      // spatial exponent coeff
constexpr float C2 = -LOG2E / 51200.0f;   // bilateral spatial coeff
constexpr float C3 = -LOG2E / 6.0f;       // bilateral intensity coeff

// LDS pool layout (bytes, 16-aligned)
constexpr int O_SSH   = 0;        // float[3136] s, linear image order
constexpr int O_GSRT  = 12544;    // float[3136] g, sorted order
                                  // (init: H u16[49][256]=25088B overlays SSH+GSRT)
constexpr int O_MSRT  = 25088;    // u16[3136]  sorted pos -> linear pixel idx
constexpr int O_OFF   = 31360;    // u32[257]   bucket offsets (pad 1040)
constexpr int O_WSX   = 32400;    // float[16][56] per-j row weights (aligned)
constexpr int O_WSY   = 35984;    // float[16][56] per-j column weights
constexpr int O_ROWC  = 39568;    // float[56][17] row-conv out (pad stride 17)
constexpr int O_XLOC  = 43376;    // int[16] x-coord of each local j
constexpr int O_WBAND = 43440;    // float[16][768] cached bilateral weights
constexpr int POOLSZ  = 92592;

#define REDUCE32(v) \
    { v += __shfl_xor(v, 1); v += __shfl_xor(v, 2); v += __shfl_xor(v, 4); \
      v += __shfl_xor(v, 8); v += __shfl_xor(v, 16); }

__global__ __launch_bounds__(NTHR) void crf_all(
    const float* __restrict__ inp,
    const float* __restrict__ spw, const float* __restrict__ blw,
    const float* __restrict__ cmw,
    float* sbufs, float* __restrict__ out)
{
    __shared__ __align__(16) unsigned char pool[POOLSZ];
    float*  s_sh  = (float*)(pool + O_SSH);
    float4* s_sh4 = (float4*)(pool + O_SSH);
    float*  g_srt = (float*)(pool + O_GSRT);
    unsigned short* m_srt = (unsigned short*)(pool + O_MSRT);
    unsigned*       offs  = (unsigned*)(pool + O_OFF);
    float*  wsx   = (float*)(pool + O_WSX);
    float*  wsy   = (float*)(pool + O_WSY);
    float*  rowc  = (float*)(pool + O_ROWC);
    int*    xloc  = (int*)(pool + O_XLOC);
    float*  wband = (float*)(pool + O_WBAND);
    unsigned short* H  = (unsigned short*)(pool + O_SSH);   // init union (25088B)
    unsigned*       Hz = (unsigned*)(pool + O_SSH);

    const int t   = threadIdx.x;
    const int bid = blockIdx.x;
    const int sub = t & 31;
    const int jl  = t >> 5;               // 0..15
    const int j   = bid * JPB + jl;
    const int xj  = j % WIMG;             // blocks may straddle rows (16 ∤ 56)
    const int yj  = j / WIMG;
    const float xjf = (float)xj, yjf = (float)yj;

    const float uj = inp[j];
    const float gj = inp[NPIX + j] * 255.0f;

    // collapse the 2x2 weight matrices to 3 scalars
    const float e0 = cmw[2] - cmw[0];
    const float e1 = cmw[3] - cmw[1];
    const float alpha = e0 * (spw[0] + blw[0]) + e1 * (spw[2] + blw[2]);
    const float beta  = e0 * (spw[1] - spw[0]) + e1 * (spw[3] - spw[2]);
    const float gamma = e0 * (blw[1] - blw[0]) + e1 * (blw[3] - blw[2]);

    // ---- I0: zero H; build aligned per-j weight tables; xloc
    for (int i = t; i < 6272; i += NTHR) Hz[i] = 0u;
    for (int idx = t; idx < JPB * 56; idx += NTHR) {
        const int jlw = idx / 56, p = idx - jlw * 56;
        const int jj = bid * JPB + jlw;
        const float ddx = (float)(jj % WIMG - p);
        const float ddy = (float)(jj / WIMG - p);
        wsx[idx] = __builtin_amdgcn_exp2f(C1 * ddx * ddx);
        wsy[idx] = __builtin_amdgcn_exp2f(C1 * ddy * ddy);
    }
    if (t < JPB) xloc[t] = (bid * JPB + t) % WIMG;
    __syncthreads();
    // ---- I1: per-chunk histogram (49 chunks x 64 px, single-owner rows)
    if (t < 49) {
        unsigned short* Hr = H + t * 256;
        const int mb = t * 64;
        for (int i = 0; i < 64; ++i) {
            int b = (int)(inp[NPIX + mb + i] * 255.0f);
            b = b > 255 ? 255 : b;
            Hr[b] = (unsigned short)(Hr[b] + 1);
        }
    }
    __syncthreads();
    // ---- I2: column prefix per bucket; totals -> offs[b]
    if (t < 256) {
        unsigned run = 0;
        for (int c = 0; c < 49; ++c) {
            unsigned short v = H[c * 256 + t];
            H[c * 256 + t] = (unsigned short)run;
            run += v;
        }
        offs[t] = run;
    }
    __syncthreads();
    // ---- I3: exclusive scan offs[0..255] (one wave, 4 buckets/lane)
    if (t < 64) {
        unsigned v0 = offs[4 * t], v1 = offs[4 * t + 1];
        unsigned v2 = offs[4 * t + 2], v3 = offs[4 * t + 3];
        unsigned sum = v0 + v1 + v2 + v3;
        unsigned sc = sum;
        for (int d = 1; d < 64; d <<= 1) {
            unsigned n = __shfl_up(sc, d);
            if (t >= d) sc += n;
        }
        unsigned base = sc - sum;
        offs[4 * t] = base;
        offs[4 * t + 1] = base + v0;
        offs[4 * t + 2] = base + v0 + v1;
        offs[4 * t + 3] = base + v0 + v1 + v2;
        if (t == 63) offs[256] = sc;               // = 3136
    }
    __syncthreads();
    // ---- I4: stable deterministic ranks -> m_srt
    if (t < 49) {
        unsigned short* Hr = H + t * 256;
        const int mb = t * 64;
        for (int i = 0; i < 64; ++i) {
            int b = (int)(inp[NPIX + mb + i] * 255.0f);
            b = b > 255 ? 255 : b;
            int r = (int)offs[b] + (int)Hr[b];
            Hr[b] = (unsigned short)(Hr[b] + 1);
            m_srt[r] = (unsigned short)(mb + i);
        }
    }
    __syncthreads();
    // ---- I5: H dead. Fill g_srt (sorted) and s_sh = u (linear).
    for (int p = t; p < NPIX; p += NTHR)
        g_srt[p] = inp[NPIX + (int)m_srt[p]] * 255.0f;
    {
        const float4* u4 = (const float4*)inp;
        for (int q = t; q < NQ; q += NTHR) s_sh4[q] = u4[q];
    }
    __syncthreads();

    // n_sp = Sx*Sy (exact separable)
    float sx, sy;
    {
        float dd = xjf - (float)sub;
        sx = __builtin_amdgcn_exp2f(C1 * dd * dd);
        if (sub + 32 < 56) {
            float d2 = xjf - (float)(sub + 32);
            sx += __builtin_amdgcn_exp2f(C1 * d2 * d2);
        }
        REDUCE32(sx);
        dd = yjf - (float)sub;
        sy = __builtin_amdgcn_exp2f(C1 * dd * dd);
        if (sub + 32 < 56) {
            float d2 = yjf - (float)(sub + 32);
            sy += __builtin_amdgcn_exp2f(C1 * d2 * d2);
        }
        REDUCE32(sy);
    }
    const float rnsp = 1.0f / (sx * sy);

    int bj = (int)gj; bj = bj > 255 ? 255 : bj;
    const int blo = (int)offs[bj < BAND ? 0 : bj - BAND];
    const int bhi = (int)offs[(bj + BAND > 255 ? 255 : bj + BAND) + 1];
    const int blen = bhi - blo;
    const int bl1 = blen < MAXB ? blen : MAXB;

    // separable spatial: truncated (+-16 tap) row conv, wave-uniform column
    // (wave w owns cols 2w,2w+1; lanes 0..55 = y), then per-j column fold.
    auto spatial = [&]() -> float {
        const int wv = t >> 6;              // wave id 0..7
        const int ln = t & 63;              // lane = y
        if (ln < 56) {
#pragma unroll
            for (int cc = 0; cc < 2; ++cc) {
                const int c = wv * 2 + cc;
                const int X = xloc[c];
                const int qlo = (X > 16) ? ((X - 16) >> 2) : 0;
                const int qhi = (X < 40) ? ((X + 16) >> 2) : 13;
                const float4* R = (const float4*)(wsx + c * 56);
                const float4* S = s_sh4 + ln * 14;
                float acc = 0.f;
                for (int q = qlo; q <= qhi; ++q) {
                    float4 w = R[q], sv = S[q];     // R: broadcast (uniform)
                    acc = fmaf(w.x, sv.x, acc); acc = fmaf(w.y, sv.y, acc);
                    acc = fmaf(w.z, sv.z, acc); acc = fmaf(w.w, sv.w, acc);
                }
                rowc[ln * 17 + c] = acc;
            }
        }
        __syncthreads();
        const float* wy = wsy + jl * 56;
        float part = wy[sub] * rowc[sub * 17 + jl];
        if (sub + 32 < 56)
            part = fmaf(wy[sub + 32], rowc[(sub + 32) * 17 + jl], part);
        REDUCE32(part);
        return part;
    };

    // publish (leader lanes, straight out of the reduce -- no pre-barrier) +
    // per-thread tight zero-sentinel spin + restage + ONE barrier.
    auto publish_sync = [&](float s, float* buf) {
        if (sub == 0)
            __hip_atomic_store(&buf[j], s, __ATOMIC_RELAXED,
                               __HIP_MEMORY_SCOPE_AGENT);
        const float4* src = (const float4*)buf;
        float4 a, b;
        const bool two = (t < Q2);
        bool da = false, db = !two;
        for (;;) {
            if (!da)
                asm volatile("global_load_dwordx4 %0, %1, off sc0 sc1"
                             : "=&v"(a) : "v"(src + t));
            if (!db)
                asm volatile("global_load_dwordx4 %0, %1, off sc0 sc1"
                             : "=&v"(b) : "v"(src + NTHR + t));
            asm volatile("s_waitcnt vmcnt(0)" ::: "memory");
            if (!da) da = (fminf(fminf(a.x, a.y), fminf(a.z, a.w)) != 0.0f);
            if (!db) db = (fminf(fminf(b.x, b.y), fminf(b.z, b.w)) != 0.0f);
            if (da && db) break;                    // exec mask narrows wave
        }
        s_sh4[t] = a;
        if (two) s_sh4[NTHR + t] = b;
        __syncthreads();                            // s_sh fully fresh
    };

    const float base = 2.0f * uj - 1.0f - alpha;
    float rnbl, s;

    // ---- iteration 0 (s = u): exact band pass, caches weights, builds n_bl
    {
        float tsp = spatial();
        float acc = 0.f, nacc = 0.f;
        float* wb = wband + jl * MAXB;
        for (int i = sub; i < blen; i += 32) {
            const int p = blo + i;
            const int m = (int)m_srt[p];
            const float gv = g_srt[p];
            const int yi = (m * 9363) >> 19;       // m/56 (exact for m<3136)
            const int xi = m - yi * 56;
            const float ux = (float)xi - xjf, vy = (float)yi - yjf;
            const float r2 = fmaf(ux, ux, vy * vy);
            const float dg = gv - gj;
            const float w = __builtin_amdgcn_exp2f(fmaf(dg * C3, dg, r2 * C2));
            if (i < MAXB) wb[i] = w;
            acc = fmaf(w, s_sh[m], acc);
            nacc += w;
        }
        REDUCE32(acc); REDUCE32(nacc);
        rnbl = 1.0f / nacc;
        float d = base - beta * (tsp * rnsp) - gamma * (acc * rnbl);
        s = 1.0f / (1.0f + __builtin_amdgcn_exp2f(-d * LOG2E));
    }
    publish_sync(s, sbufs);

    // ---- iterations 1..9: cached-weight band pass
    for (int k = 1; k < 10; ++k) {
        float tsp = spatial();
        float acc = 0.f;
        const float* wb = wband + jl * MAXB;
        for (int i = sub; i < bl1; i += 32) {
            const float w = wb[i];
            const int m = (int)m_srt[blo + i];
            acc = fmaf(w, s_sh[m], acc);
        }
        for (int i = MAXB + sub; i < blen; i += 32) {   // overflow fallback
            const int p = blo + i;
            const int m = (int)m_srt[p];
            const float gv = g_srt[p];
            const int yi = (m * 9363) >> 19;
            const int xi = m - yi * 56;
            const float ux = (float)xi - xjf, vy = (float)yi - yjf;
            const float r2 = fmaf(ux, ux, vy * vy);
            const float dg = gv - gj;
            const float w = __builtin_amdgcn_exp2f(fmaf(dg * C3, dg, r2 * C2));
            acc = fmaf(w, s_sh[m], acc);
        }
        REDUCE32(acc);
        float d = base - beta * (tsp * rnsp) - gamma * (acc * rnbl);
        s = 1.0f / (1.0f + __builtin_amdgcn_exp2f(-d * LOG2E));
        if (k < 9) publish_sync(s, sbufs + k * NPIX);
        else if (sub == 0) out[j] = s;   // softmax(q)[1] = sigmoid(d)
    }
}

}  // namespace

extern "C" void kernel_launch(void* const* d_in, const int* in_sizes, int n_in,
                              void* d_out, int out_size, void* d_ws, size_t ws_size,
                              hipStream_t stream) {
    const float* inp = (const float*)d_in[0];
    const float* spw = (const float*)d_in[1];
    const float* blw = (const float*)d_in[2];
    const float* cmw = (const float*)d_in[3];
    float* sbufs = (float*)d_ws;          // 9 x 3136 floats, zero = "not yet"
    float* out = (float*)d_out;

    hipMemsetAsync(sbufs, 0, NBUF * NPIX * sizeof(float), stream);
    crf_all<<<dim3(NBLK), dim3(NTHR), 0, stream>>>(inp, spw, blw, cmw,
                                                   sbufs, out);
}

// Round 17
// 66.018 us; speedup vs baseline: 1.1589x; 1.1589x over previous
//
#include <hip/hip_runtime.h>

// CRF-RNN (C=2) on 56x56, 10 iterations in ONE kernel, plain launch.
// 196 blocks x 512 thr (8 waves) -> exactly 1 block/CU, 2 waves/SIMD.
//
// Math: s = sigmoid(q1-q0); d = (2u-1) - alpha - beta*t_sp/n_sp - gamma*t_bl/n_bl.
//  * spatial separable: 56-tap row conv + column fold; n_sp = Sx*Sy.
//    Row conv mapping (r17): wave w owns local-j cols {2w,2w+1}, lanes = y.
//    Each thread register-caches its s-row ONCE (14 unrolled ds_read_b128)
//    and reuses it for both cols; weight reads are wave-uniform float4 ->
//    LDS broadcast (free). 4x less LDS traffic than r15, same unrolled ILP
//    (r16 lost 11us by un-unrolling this loop -- lesson applied).
//  * bilateral: theta_beta=3 -> weight < 5e-17 outside +-16 intensity
//    buckets. Counting sort ONCE; band loop walks m_srt[p] (u16), reads
//    s_sh[m] directly (magic-mul recovers x,y). Exact formula every iter.
//  * norms s-independent: iter-0 computes them, reciprocals in registers.
//
// Sync (r15, proven): zero-sentinel flow control, per-thread tight spin.
// Publish = leader lanes store s right out of the reduce (relaxed agent scope
// -> LLC, no cache maintenance), no pre-barrier (safe: detection of all-3136
// transitively implies every lane finished reading old state). Poll = each
// thread re-issues its 1-2 quad loads (sc0 sc1) immediately. One barrier.

namespace {

constexpr int NPIX = 3136;
constexpr int WIMG = 56;
constexpr int JPB  = 16;              // j-pixels per block
constexpr int NBLK = NPIX / JPB;      // 196 blocks = 1 per CU
constexpr int NTHR = 512;             // 8 waves
constexpr int NQ   = NPIX / 4;        // 784 quads
constexpr int NBUF = 9;               // publish buffers (syncs after iters 0..8)
constexpr int BAND = 16;              // intensity band (buckets)
constexpr int Q2   = NQ - NTHR;       // 272 threads own a second quad

constexpr float LOG2E = 1.4426950408889634f;
constexpr float C1 = -LOG2E / 18.0f;      // spatial exponent coeff
constexpr float C2 = -LOG2E / 51200.0f;   // bilateral spatial coeff
constexpr float C3 = -LOG2E / 6.0f;       // bilateral intensity coeff

// LDS pool layout (bytes, 16-aligned)
constexpr int O_SSH  = 0;         // float[3136] s, linear image order
constexpr int O_GSRT = 12544;     // float[3136] g, sorted order
                                  // (init: H u16[49][256]=25088B overlays SSH+GSRT)
constexpr int O_MSRT = 25088;     // u16[3136]  sorted pos -> linear pixel idx
constexpr int O_OFF  = 31360;     // u32[257]   bucket offsets (pad 1040)
constexpr int O_WSX  = 32400;     // float[16][56] per-j row weights (aligned)
constexpr int O_WSY  = 35984;     // float[16][56] per-j column weights
constexpr int O_ROWC = 39568;     // float[56][17] row-conv out (pad stride 17)
constexpr int POOLSZ = 43376;

#define REDUCE32(v) \
    { v += __shfl_xor(v, 1); v += __shfl_xor(v, 2); v += __shfl_xor(v, 4); \
      v += __shfl_xor(v, 8); v += __shfl_xor(v, 16); }

__global__ __launch_bounds__(NTHR) void crf_all(
    const float* __restrict__ inp,
    const float* __restrict__ spw, const float* __restrict__ blw,
    const float* __restrict__ cmw,
    float* sbufs, float* __restrict__ out)
{
    __shared__ __align__(16) unsigned char pool[POOLSZ];
    float*  s_sh  = (float*)(pool + O_SSH);
    float4* s_sh4 = (float4*)(pool + O_SSH);
    float*  g_srt = (float*)(pool + O_GSRT);
    unsigned short* m_srt = (unsigned short*)(pool + O_MSRT);
    unsigned*       offs  = (unsigned*)(pool + O_OFF);
    float*  wsx   = (float*)(pool + O_WSX);
    float*  wsy   = (float*)(pool + O_WSY);
    float*  rowc  = (float*)(pool + O_ROWC);
    unsigned short* H  = (unsigned short*)(pool + O_SSH);   // init union (25088B)
    unsigned*       Hz = (unsigned*)(pool + O_SSH);

    const int t   = threadIdx.x;
    const int bid = blockIdx.x;
    const int sub = t & 31;
    const int jl  = t >> 5;               // 0..15
    const int j   = bid * JPB + jl;
    const int xj  = j % WIMG;             // blocks may straddle rows (16 ∤ 56)
    const int yj  = j / WIMG;
    const float xjf = (float)xj, yjf = (float)yj;

    const float uj = inp[j];
    const float gj = inp[NPIX + j] * 255.0f;

    // collapse the 2x2 weight matrices to 3 scalars
    const float e0 = cmw[2] - cmw[0];
    const float e1 = cmw[3] - cmw[1];
    const float alpha = e0 * (spw[0] + blw[0]) + e1 * (spw[2] + blw[2]);
    const float beta  = e0 * (spw[1] - spw[0]) + e1 * (spw[3] - spw[2]);
    const float gamma = e0 * (blw[1] - blw[0]) + e1 * (blw[3] - blw[2]);

    // ---- I0: zero H; build aligned per-j weight tables (outside H region)
    for (int i = t; i < 6272; i += NTHR) Hz[i] = 0u;
    for (int idx = t; idx < JPB * 56; idx += NTHR) {
        const int jlw = idx / 56, p = idx - jlw * 56;
        const int jj = bid * JPB + jlw;
        const float ddx = (float)(jj % WIMG - p);
        const float ddy = (float)(jj / WIMG - p);
        wsx[idx] = __builtin_amdgcn_exp2f(C1 * ddx * ddx);
        wsy[idx] = __builtin_amdgcn_exp2f(C1 * ddy * ddy);
    }
    __syncthreads();
    // ---- I1: per-chunk histogram (49 chunks x 64 px, single-owner rows)
    if (t < 49) {
        unsigned short* Hr = H + t * 256;
        const int mb = t * 64;
        for (int i = 0; i < 64; ++i) {
            int b = (int)(inp[NPIX + mb + i] * 255.0f);
            b = b > 255 ? 255 : b;
            Hr[b] = (unsigned short)(Hr[b] + 1);
        }
    }
    __syncthreads();
    // ---- I2: column prefix per bucket; totals -> offs[b]
    if (t < 256) {
        unsigned run = 0;
        for (int c = 0; c < 49; ++c) {
            unsigned short v = H[c * 256 + t];
            H[c * 256 + t] = (unsigned short)run;
            run += v;
        }
        offs[t] = run;
    }
    __syncthreads();
    // ---- I3: exclusive scan offs[0..255] (one wave, 4 buckets/lane)
    if (t < 64) {
        unsigned v0 = offs[4 * t], v1 = offs[4 * t + 1];
        unsigned v2 = offs[4 * t + 2], v3 = offs[4 * t + 3];
        unsigned sum = v0 + v1 + v2 + v3;
        unsigned sc = sum;
        for (int d = 1; d < 64; d <<= 1) {
            unsigned n = __shfl_up(sc, d);
            if (t >= d) sc += n;
        }
        unsigned base = sc - sum;
        offs[4 * t] = base;
        offs[4 * t + 1] = base + v0;
        offs[4 * t + 2] = base + v0 + v1;
        offs[4 * t + 3] = base + v0 + v1 + v2;
        if (t == 63) offs[256] = sc;               // = 3136
    }
    __syncthreads();
    // ---- I4: stable deterministic ranks -> m_srt
    if (t < 49) {
        unsigned short* Hr = H + t * 256;
        const int mb = t * 64;
        for (int i = 0; i < 64; ++i) {
            int b = (int)(inp[NPIX + mb + i] * 255.0f);
            b = b > 255 ? 255 : b;
            int r = (int)offs[b] + (int)Hr[b];
            Hr[b] = (unsigned short)(Hr[b] + 1);
            m_srt[r] = (unsigned short)(mb + i);
        }
    }
    __syncthreads();
    // ---- I5: H dead. Fill g_srt (sorted) and s_sh = u (linear).
    for (int p = t; p < NPIX; p += NTHR)
        g_srt[p] = inp[NPIX + (int)m_srt[p]] * 255.0f;
    {
        const float4* u4 = (const float4*)inp;
        for (int q = t; q < NQ; q += NTHR) s_sh4[q] = u4[q];
    }
    __syncthreads();

    // n_sp = Sx*Sy (exact separable)
    float sx, sy;
    {
        float dd = xjf - (float)sub;
        sx = __builtin_amdgcn_exp2f(C1 * dd * dd);
        if (sub + 32 < 56) {
            float d2 = xjf - (float)(sub + 32);
            sx += __builtin_amdgcn_exp2f(C1 * d2 * d2);
        }
        REDUCE32(sx);
        dd = yjf - (float)sub;
        sy = __builtin_amdgcn_exp2f(C1 * dd * dd);
        if (sub + 32 < 56) {
            float d2 = yjf - (float)(sub + 32);
            sy += __builtin_amdgcn_exp2f(C1 * d2 * d2);
        }
        REDUCE32(sy);
    }
    const float rnsp = 1.0f / (sx * sy);

    int bj = (int)gj; bj = bj > 255 ? 255 : bj;
    const int blo = (int)offs[bj < BAND ? 0 : bj - BAND];
    const int bhi = (int)offs[(bj + BAND > 255 ? 255 : bj + BAND) + 1];

    // separable spatial row conv: wave w -> local-j cols {2w,2w+1}, lane = y.
    // s-row register-cached once (unrolled b128 reads, full ILP); weight
    // reads wave-uniform float4 -> LDS broadcast. Then per-j column fold.
    auto spatial = [&]() -> float {
        const int wv = t >> 6;              // wave id 0..7
        const int ln = t & 63;              // lane = y
        if (ln < 56) {
            const float4* S = s_sh4 + ln * 14;
            float4 sv[14];
#pragma unroll
            for (int q = 0; q < 14; ++q) sv[q] = S[q];
#pragma unroll
            for (int cc = 0; cc < 2; ++cc) {
                const int c = wv * 2 + cc;
                const float4* R = (const float4*)(wsx + c * 56);  // uniform
                float acc = 0.f;
#pragma unroll
                for (int q = 0; q < 14; ++q) {
                    float4 w = R[q];
                    acc = fmaf(w.x, sv[q].x, acc); acc = fmaf(w.y, sv[q].y, acc);
                    acc = fmaf(w.z, sv[q].z, acc); acc = fmaf(w.w, sv[q].w, acc);
                }
                rowc[ln * 17 + c] = acc;
            }
        }
        __syncthreads();
        const float* wy = wsy + jl * 56;
        float part = wy[sub] * rowc[sub * 17 + jl];
        if (sub + 32 < 56)
            part = fmaf(wy[sub + 32], rowc[(sub + 32) * 17 + jl], part);
        REDUCE32(part);
        return part;
    };

    // bilateral band pass over sorted positions [blo,bhi), stride 32
    auto bilateral = [&](float* nacc_out) -> float {
        float acc = 0.f, nacc = 0.f;
        for (int p = blo + sub; p < bhi; p += 32) {
            const int m = (int)m_srt[p];
            const float gv = g_srt[p];
            const float sv = s_sh[m];
            const int yi = (m * 9363) >> 19;       // m/56 (exact for m<3136)
            const int xi = m - yi * 56;
            const float ux = (float)xi - xjf, vy = (float)yi - yjf;
            const float r2 = fmaf(ux, ux, vy * vy);
            const float dg = gv - gj;
            const float w = __builtin_amdgcn_exp2f(fmaf(dg * C3, dg, r2 * C2));
            acc = fmaf(w, sv, acc);
            if (nacc_out) nacc += w;
        }
        REDUCE32(acc);
        if (nacc_out) { REDUCE32(nacc); *nacc_out = nacc; }
        return acc;
    };

    // publish (leader lanes, straight out of the reduce -- no pre-barrier) +
    // per-thread tight zero-sentinel spin + restage + ONE barrier.
    // Safety: detection of all-3136-published transitively implies every
    // 32-lane group everywhere completed its shfl-reduce, hence all reads
    // of the old s_sh have executed.
    auto publish_sync = [&](float s, float* buf) {
        if (sub == 0)
            __hip_atomic_store(&buf[j], s, __ATOMIC_RELAXED,
                               __HIP_MEMORY_SCOPE_AGENT);
        const float4* src = (const float4*)buf;
        float4 a, b;
        const bool two = (t < Q2);
        bool da = false, db = !two;
        for (;;) {
            if (!da)
                asm volatile("global_load_dwordx4 %0, %1, off sc0 sc1"
                             : "=&v"(a) : "v"(src + t));
            if (!db)
                asm volatile("global_load_dwordx4 %0, %1, off sc0 sc1"
                             : "=&v"(b) : "v"(src + NTHR + t));
            asm volatile("s_waitcnt vmcnt(0)" ::: "memory");
            if (!da) da = (fminf(fminf(a.x, a.y), fminf(a.z, a.w)) != 0.0f);
            if (!db) db = (fminf(fminf(b.x, b.y), fminf(b.z, b.w)) != 0.0f);
            if (da && db) break;                    // exec mask narrows wave
        }
        s_sh4[t] = a;
        if (two) s_sh4[NTHR + t] = b;
        __syncthreads();                            // s_sh fully fresh
    };

    const float base = 2.0f * uj - 1.0f - alpha;
    float rnbl, s;

    // ---- iteration 0 (s = u), also accumulates n_bl over the band
    {
        float tsp = spatial();
        float nacc;
        float acc = bilateral(&nacc);
        rnbl = 1.0f / nacc;
        float d = base - beta * (tsp * rnsp) - gamma * (acc * rnbl);
        s = 1.0f / (1.0f + __builtin_amdgcn_exp2f(-d * LOG2E));
    }
    publish_sync(s, sbufs);

    // ---- iterations 1..9
    for (int k = 1; k < 10; ++k) {
        float tsp = spatial();
        float acc = bilateral(nullptr);
        float d = base - beta * (tsp * rnsp) - gamma * (acc * rnbl);
        s = 1.0f / (1.0f + __builtin_amdgcn_exp2f(-d * LOG2E));
        if (k < 9) publish_sync(s, sbufs + k * NPIX);
        else if (sub == 0) out[j] = s;   // softmax(q)[1] = sigmoid(d)
    }
}

}  // namespace

extern "C" void kernel_launch(void* const* d_in, const int* in_sizes, int n_in,
                              void* d_out, int out_size, void* d_ws, size_t ws_size,
                              hipStream_t stream) {
    const float* inp = (const float*)d_in[0];
    const float* spw = (const float*)d_in[1];
    const float* blw = (const float*)d_in[2];
    const float* cmw = (const float*)d_in[3];
    float* sbufs = (float*)d_ws;          // 9 x 3136 floats, zero = "not yet"
    float* out = (float*)d_out;

    hipMemsetAsync(sbufs, 0, NBUF * NPIX * sizeof(float), stream);
    crf_all<<<dim3(NBLK), dim3(NTHR), 0, stream>>>(inp, spw, blw, cmw,
                                                   sbufs, out);
}

// Round 18
// 63.724 us; speedup vs baseline: 1.2007x; 1.0360x over previous
//
#include <hip/hip_runtime.h>

// CRF-RNN (C=2) on 56x56, 10 iterations in ONE kernel, plain launch.
// 196 blocks x 512 thr (8 waves) -> exactly 1 block/CU, 2 waves/SIMD.
//
// Math: s = sigmoid(q1-q0); d = (2u-1) - alpha - beta*t_sp/n_sp - gamma*t_bl/n_bl.
//  * spatial separable: row conv (wave w owns local-j cols {2w,2w+1}, lane=y,
//    s-row register-cached, weights wave-uniform/broadcast) + IN-WAVE weighted
//    64-lane butterfly fold (r18: deletes rowc[] and the per-iter internal
//    barrier). n_sp = Sx*Sy exactly.
//  * bilateral: 128 intensity bins (2 levels/bin); band = +-9 bins, a strict
//    superset of the previous +-16-intensity band (weight <3e-19 outside).
//    Counting sort ONCE. r18: I1 = 98 chunks x 32 px (serial RMW chain halved)
//    saving lidx[m]; I4 = fully parallel rank = offs[bin]+H[chunk][bin]+lidx.
//    Band loop 4-way unrolled to amortize the m_srt->s_sh dependent chain.
//  * norms s-independent: iter-0 computes them, reciprocals in registers.
//
// Sync (r15, proven): zero-sentinel flow control, per-thread tight spin.
// Publish = leader lanes store s right out of the reduce (relaxed agent scope
// -> LLC, no cache maintenance), no pre-barrier (safe: detection of all-3136
// implies every WAVE everywhere completed its reads -- both groups of a wave
// are lockstep). Poll = each thread re-issues its 1-2 quad loads (sc0 sc1)
// immediately. Restage + ONE barrier per iteration.

namespace {

constexpr int NPIX = 3136;
constexpr int WIMG = 56;
constexpr int JPB  = 16;              // j-pixels per block
constexpr int NBLK = NPIX / JPB;      // 196 blocks = 1 per CU
constexpr int NTHR = 512;             // 8 waves
constexpr int NQ   = NPIX / 4;        // 784 quads
constexpr int NBUF = 9;               // publish buffers (syncs after iters 0..8)
constexpr int Q2   = NQ - NTHR;       // 272 threads own a second quad
constexpr int NBIN = 128;             // intensity bins (2 levels each)
constexpr int BANDB = 9;              // band radius in bins (covers dg>=16)
constexpr int NCHK = 98;              // histogram chunks
constexpr int CPX  = 32;              // pixels per chunk

constexpr float LOG2E = 1.4426950408889634f;
constexpr float C1 = -LOG2E / 18.0f;      // spatial exponent coeff
constexpr float C2 = -LOG2E / 51200.0f;   // bilateral spatial coeff
constexpr float C3 = -LOG2E / 6.0f;       // bilateral intensity coeff

// LDS pool layout (bytes, 16-aligned)
constexpr int O_SSH  = 0;         // float[3136] s, linear (init: H u16[98][128])
constexpr int O_GSRT = 12544;     // float[3136] g, sorted (init: H continued)
constexpr int O_MSRT = 25088;     // u16[3136]  sorted pos -> linear pixel idx
constexpr int O_OFF  = 31360;     // u32[129]   bin offsets (pad 528)
constexpr int O_WSX  = 31888;     // float[16][56] per-j row weights (aligned)
constexpr int O_WSY  = 35472;     // float[16][56] per-j column weights
constexpr int O_LIDX = 39056;     // u8[3136]   rank within (chunk,bin)
constexpr int POOLSZ = 42192;

#define REDUCE32(v) \
    { v += __shfl_xor(v, 1); v += __shfl_xor(v, 2); v += __shfl_xor(v, 4); \
      v += __shfl_xor(v, 8); v += __shfl_xor(v, 16); }
#define REDUCE64(v) \
    { v += __shfl_xor(v, 1); v += __shfl_xor(v, 2); v += __shfl_xor(v, 4); \
      v += __shfl_xor(v, 8); v += __shfl_xor(v, 16); v += __shfl_xor(v, 32); }

__global__ __launch_bounds__(NTHR) void crf_all(
    const float* __restrict__ inp,
    const float* __restrict__ spw, const float* __restrict__ blw,
    const float* __restrict__ cmw,
    float* sbufs, float* __restrict__ out)
{
    __shared__ __align__(16) unsigned char pool[POOLSZ];
    float*  s_sh  = (float*)(pool + O_SSH);
    float4* s_sh4 = (float4*)(pool + O_SSH);
    float*  g_srt = (float*)(pool + O_GSRT);
    unsigned short* m_srt = (unsigned short*)(pool + O_MSRT);
    unsigned*       offs  = (unsigned*)(pool + O_OFF);
    float*  wsx   = (float*)(pool + O_WSX);
    float*  wsy   = (float*)(pool + O_WSY);
    unsigned char*  lidx = (unsigned char*)(pool + O_LIDX);
    unsigned short* H  = (unsigned short*)(pool + O_SSH);   // init union (25088B)
    unsigned*       Hz = (unsigned*)(pool + O_SSH);

    const int t   = threadIdx.x;
    const int bid = blockIdx.x;
    const int sub = t & 31;
    const int jl  = t >> 5;               // 0..15
    const int j   = bid * JPB + jl;
    const int xj  = j % WIMG;             // blocks may straddle rows (16 ∤ 56)
    const int yj  = j / WIMG;
    const float xjf = (float)xj, yjf = (float)yj;

    const float uj = inp[j];
    const float gj = inp[NPIX + j] * 255.0f;

    // collapse the 2x2 weight matrices to 3 scalars
    const float e0 = cmw[2] - cmw[0];
    const float e1 = cmw[3] - cmw[1];
    const float alpha = e0 * (spw[0] + blw[0]) + e1 * (spw[2] + blw[2]);
    const float beta  = e0 * (spw[1] - spw[0]) + e1 * (spw[3] - spw[2]);
    const float gamma = e0 * (blw[1] - blw[0]) + e1 * (blw[3] - blw[2]);

    // ---- I0: zero H; build aligned per-j weight tables (outside H region)
    for (int i = t; i < 6272; i += NTHR) Hz[i] = 0u;
    for (int idx = t; idx < JPB * 56; idx += NTHR) {
        const int jlw = idx / 56, p = idx - jlw * 56;
        const int jj = bid * JPB + jlw;
        const float ddx = (float)(jj % WIMG - p);
        const float ddy = (float)(jj / WIMG - p);
        wsx[idx] = __builtin_amdgcn_exp2f(C1 * ddx * ddx);
        wsy[idx] = __builtin_amdgcn_exp2f(C1 * ddy * ddy);
    }
    __syncthreads();
    // ---- I1: per-chunk histogram, saving local index (98 chunks x 32 px)
    if (t < NCHK) {
        unsigned short* Hr = H + t * NBIN;
        const int mb = t * CPX;
        for (int i = 0; i < CPX; ++i) {
            int b = (int)(inp[NPIX + mb + i] * 255.0f);
            b = (b > 255 ? 255 : b) >> 1;
            lidx[mb + i] = (unsigned char)Hr[b];
            Hr[b] = (unsigned short)(Hr[b] + 1);
        }
    }
    __syncthreads();
    // ---- I2: column prefix per bin over chunks; totals -> offs[b]
    if (t < NBIN) {
        unsigned run = 0;
        for (int c = 0; c < NCHK; ++c) {
            unsigned short v = H[c * NBIN + t];
            H[c * NBIN + t] = (unsigned short)run;
            run += v;
        }
        offs[t] = run;
    }
    __syncthreads();
    // ---- I3: exclusive scan offs[0..127] (one wave, 2 bins/lane)
    if (t < 64) {
        unsigned v0 = offs[2 * t], v1 = offs[2 * t + 1];
        unsigned sum = v0 + v1;
        unsigned sc = sum;
        for (int d = 1; d < 64; d <<= 1) {
            unsigned n = __shfl_up(sc, d);
            if (t >= d) sc += n;
        }
        unsigned base = sc - sum;
        offs[2 * t] = base;
        offs[2 * t + 1] = base + v0;
        if (t == 63) offs[NBIN] = sc;              // = 3136
    }
    __syncthreads();
    // ---- I4: PARALLEL ranks -> m_srt (read-only: offs + chunk prefix + lidx)
    for (int m = t; m < NPIX; m += NTHR) {
        int b = (int)(inp[NPIX + m] * 255.0f);
        b = (b > 255 ? 255 : b) >> 1;
        const int r = (int)offs[b] + (int)H[(m >> 5) * NBIN + b] + (int)lidx[m];
        m_srt[r] = (unsigned short)m;
    }
    __syncthreads();
    // ---- I5: H dead. Fill g_srt (sorted) and s_sh = u (linear).
    for (int p = t; p < NPIX; p += NTHR)
        g_srt[p] = inp[NPIX + (int)m_srt[p]] * 255.0f;
    {
        const float4* u4 = (const float4*)inp;
        for (int q = t; q < NQ; q += NTHR) s_sh4[q] = u4[q];
    }
    __syncthreads();

    // n_sp = Sx*Sy (exact separable)
    float sx, sy;
    {
        float dd = xjf - (float)sub;
        sx = __builtin_amdgcn_exp2f(C1 * dd * dd);
        if (sub + 32 < 56) {
            float d2 = xjf - (float)(sub + 32);
            sx += __builtin_amdgcn_exp2f(C1 * d2 * d2);
        }
        REDUCE32(sx);
        dd = yjf - (float)sub;
        sy = __builtin_amdgcn_exp2f(C1 * dd * dd);
        if (sub + 32 < 56) {
            float d2 = yjf - (float)(sub + 32);
            sy += __builtin_amdgcn_exp2f(C1 * d2 * d2);
        }
        REDUCE32(sy);
    }
    const float rnsp = 1.0f / (sx * sy);

    int bj = (int)gj; bj = (bj > 255 ? 255 : bj) >> 1;
    const int b0 = bj < BANDB ? 0 : bj - BANDB;
    const int b1 = bj + BANDB > NBIN - 1 ? NBIN - 1 : bj + BANDB;
    const int blo = (int)offs[b0];
    const int bhi = (int)offs[b1 + 1];

    // spatial: wave w computes cols {2w,2w+1} (lane=y, s-row reg-cached,
    // uniform weight reads) then folds IN-WAVE via weighted 64-lane butterfly.
    auto spatial = [&]() -> float {
        const int wv = t >> 6;              // wave id 0..7
        const int ln = t & 63;              // lane = y
        float v0 = 0.f, v1 = 0.f;
        if (ln < 56) {
            const float4* S = s_sh4 + ln * 14;
            float4 sv[14];
#pragma unroll
            for (int q = 0; q < 14; ++q) sv[q] = S[q];
            const int c0 = wv * 2, c1 = c0 + 1;
            const float4* R0 = (const float4*)(wsx + c0 * 56);  // uniform
            const float4* R1 = (const float4*)(wsx + c1 * 56);
            float a0 = 0.f, a1 = 0.f;
#pragma unroll
            for (int q = 0; q < 14; ++q) {
                float4 w0 = R0[q], w1 = R1[q];
                a0 = fmaf(w0.x, sv[q].x, a0); a0 = fmaf(w0.y, sv[q].y, a0);
                a0 = fmaf(w0.z, sv[q].z, a0); a0 = fmaf(w0.w, sv[q].w, a0);
                a1 = fmaf(w1.x, sv[q].x, a1); a1 = fmaf(w1.y, sv[q].y, a1);
                a1 = fmaf(w1.z, sv[q].z, a1); a1 = fmaf(w1.w, sv[q].w, a1);
            }
            v0 = wsy[c0 * 56 + ln] * a0;    // column weight for y=ln
            v1 = wsy[c1 * 56 + ln] * a1;
        }
        REDUCE64(v0); REDUCE64(v1);
        return (ln < 32) ? v0 : v1;         // lanes 0-31: jl=2w; 32-63: 2w+1
    };

    // bilateral band pass, 4-way unrolled (amortizes m_srt->s_sh LDS chain)
    auto bilateral = [&](float* nacc_out) -> float {
        float acc = 0.f, nacc = 0.f;
        int p = blo + sub;
#define BIL_BODY(MM, GG, SS) { \
            const int yi = (MM * 9363) >> 19; \
            const int xi = MM - yi * 56; \
            const float ux = (float)xi - xjf, vy = (float)yi - yjf; \
            const float r2 = fmaf(ux, ux, vy * vy); \
            const float dg = GG - gj; \
            const float w = __builtin_amdgcn_exp2f(fmaf(dg * C3, dg, r2 * C2)); \
            acc = fmaf(w, SS, acc); \
            if (nacc_out) nacc += w; }
        for (; p + 96 < bhi; p += 128) {
            const int m0 = m_srt[p],      m1 = m_srt[p + 32];
            const int m2 = m_srt[p + 64], m3 = m_srt[p + 96];
            const float g0 = g_srt[p],      g1 = g_srt[p + 32];
            const float g2 = g_srt[p + 64], g3 = g_srt[p + 96];
            const float s0 = s_sh[m0], s1 = s_sh[m1];
            const float s2 = s_sh[m2], s3 = s_sh[m3];
            BIL_BODY(m0, g0, s0) BIL_BODY(m1, g1, s1)
            BIL_BODY(m2, g2, s2) BIL_BODY(m3, g3, s3)
        }
        for (; p < bhi; p += 32) {
            const int mm = (int)m_srt[p];
            const float gg = g_srt[p];
            const float ss = s_sh[mm];
            BIL_BODY(mm, gg, ss)
        }
#undef BIL_BODY
        REDUCE32(acc);
        if (nacc_out) { REDUCE32(nacc); *nacc_out = nacc; }
        return acc;
    };

    // publish (leader lanes, straight out of the reduce -- no pre-barrier) +
    // per-thread tight zero-sentinel spin + restage + ONE barrier.
    auto publish_sync = [&](float s, float* buf) {
        if (sub == 0)
            __hip_atomic_store(&buf[j], s, __ATOMIC_RELAXED,
                               __HIP_MEMORY_SCOPE_AGENT);
        const float4* src = (const float4*)buf;
        float4 a, b;
        const bool two = (t < Q2);
        bool da = false, db = !two;
        for (;;) {
            if (!da)
                asm volatile("global_load_dwordx4 %0, %1, off sc0 sc1"
                             : "=&v"(a) : "v"(src + t));
            if (!db)
                asm volatile("global_load_dwordx4 %0, %1, off sc0 sc1"
                             : "=&v"(b) : "v"(src + NTHR + t));
            asm volatile("s_waitcnt vmcnt(0)" ::: "memory");
            if (!da) da = (fminf(fminf(a.x, a.y), fminf(a.z, a.w)) != 0.0f);
            if (!db) db = (fminf(fminf(b.x, b.y), fminf(b.z, b.w)) != 0.0f);
            if (da && db) break;                    // exec mask narrows wave
        }
        s_sh4[t] = a;
        if (two) s_sh4[NTHR + t] = b;
        __syncthreads();                            // s_sh fully fresh
    };

    const float base = 2.0f * uj - 1.0f - alpha;
    float rnbl, s;

    // ---- iteration 0 (s = u), also accumulates n_bl over the band
    {
        float tsp = spatial();
        float nacc;
        float acc = bilateral(&nacc);
        rnbl = 1.0f / nacc;
        float d = base - beta * (tsp * rnsp) - gamma * (acc * rnbl);
        s = 1.0f / (1.0f + __builtin_amdgcn_exp2f(-d * LOG2E));
    }
    publish_sync(s, sbufs);

    // ---- iterations 1..9
    for (int k = 1; k < 10; ++k) {
        float tsp = spatial();
        float acc = bilateral(nullptr);
        float d = base - beta * (tsp * rnsp) - gamma * (acc * rnbl);
        s = 1.0f / (1.0f + __builtin_amdgcn_exp2f(-d * LOG2E));
        if (k < 9) publish_sync(s, sbufs + k * NPIX);
        else if (sub == 0) out[j] = s;   // softmax(q)[1] = sigmoid(d)
    }
}

}  // namespace

extern "C" void kernel_launch(void* const* d_in, const int* in_sizes, int n_in,
                              void* d_out, int out_size, void* d_ws, size_t ws_size,
                              hipStream_t stream) {
    const float* inp = (const float*)d_in[0];
    const float* spw = (const float*)d_in[1];
    const float* blw = (const float*)d_in[2];
    const float* cmw = (const float*)d_in[3];
    float* sbufs = (float*)d_ws;          // 9 x 3136 floats, zero = "not yet"
    float* out = (float*)d_out;

    hipMemsetAsync(sbufs, 0, NBUF * NPIX * sizeof(float), stream);
    crf_all<<<dim3(NBLK), dim3(NTHR), 0, stream>>>(inp, spw, blw, cmw,
                                                   sbufs, out);
}